// Round 4
// baseline (1144.642 us; speedup 1.0000x reference)
//
#include <hip/hip_runtime.h>
#include <hip/hip_bf16.h>
#include <cstdint>
#include <cstddef>

#define T_TOK 4096
#define DMODEL 1024
#define HIDDEN 2048
#define NEXP 8     // routed experts; index 8 = shared
#define CAPA 1280  // per-expert slot capacity (mult of 256; mean 1024, sd ~30 -> +8.6 sigma)

typedef __bf16 bf16_t;
typedef bf16_t bf16x8 __attribute__((ext_vector_type(8)));
typedef float f32x4 __attribute__((ext_vector_type(4)));

__device__ __forceinline__ void gl_lds16(const void* g, void* l) {
    __builtin_amdgcn_global_load_lds(
        (const __attribute__((address_space(1))) unsigned int*)g,
        (__attribute__((address_space(3))) unsigned int*)l, 16, 0, 0);
}

// ---------------- x f32 -> bf16 ----------------
__global__ __launch_bounds__(256) void cvt_x_kernel(const float* __restrict__ x,
                                                    bf16_t* __restrict__ xb, int n8) {
    int i = blockIdx.x * 256 + threadIdx.x;
    if (i >= n8) return;
    const float4* v = (const float4*)(x + (size_t)i * 8);
    float4 a = v[0], b = v[1];
    bf16x8 o = {(bf16_t)a.x, (bf16_t)a.y, (bf16_t)a.z, (bf16_t)a.w,
                (bf16_t)b.x, (bf16_t)b.y, (bf16_t)b.z, (bf16_t)b.w};
    *(bf16x8*)(xb + (size_t)i * 8) = o;
}

// ---------------- router ----------------
__global__ __launch_bounds__(256) void router_kernel(const float* __restrict__ x,
                                                     const float* __restrict__ wr,
                                                     int* __restrict__ cnt,
                                                     int* __restrict__ tok,
                                                     float* __restrict__ gate,
                                                     int2* __restrict__ pair) {
    int token = (blockIdx.x * 256 + threadIdx.x) >> 6;
    int lane = threadIdx.x & 63;
    if (token >= T_TOK) return;
    const float* xr = x + (size_t)token * DMODEL;
    float acc[8];
#pragma unroll
    for (int e = 0; e < 8; e++) acc[e] = 0.f;
    for (int d = lane; d < DMODEL; d += 64) {
        float xv = xr[d];
        const float* w = wr + d * 8;
#pragma unroll
        for (int e = 0; e < 8; e++) acc[e] += xv * w[e];
    }
#pragma unroll
    for (int e = 0; e < 8; e++) {
#pragma unroll
        for (int off = 32; off > 0; off >>= 1) acc[e] += __shfl_down(acc[e], off);
    }
    if (lane == 0) {
        int i1 = 0; float v1 = acc[0];
#pragma unroll
        for (int e = 1; e < 8; e++) if (acc[e] > v1) { v1 = acc[e]; i1 = e; }
        int i2 = -1; float v2 = -1e30f;
#pragma unroll
        for (int e = 0; e < 8; e++) if (e != i1 && acc[e] > v2) { v2 = acc[e]; i2 = e; }
        float g1 = 1.f / (1.f + __expf(v2 - v1));
        float g2 = 1.f - g1;
        int p1 = atomicAdd(&cnt[i1], 1);
        int px = -1, py = -1;
        if (p1 < CAPA) {
            tok[(size_t)i1 * CAPA + p1] = token; gate[(size_t)i1 * CAPA + p1] = g1;
            px = i1 * CAPA + p1;
        }
        int p2 = atomicAdd(&cnt[i2], 1);
        if (p2 < CAPA) {
            tok[(size_t)i2 * CAPA + p2] = token; gate[(size_t)i2 * CAPA + p2] = g2;
            py = i2 * CAPA + p2;
        }
        pair[token] = make_int2(px, py);
    }
}

// ---------------- transpose+cvt: f32 [R][C] -> bf16 [C][R] ----------------
__global__ __launch_bounds__(256) void transpose_cvt_kernel(const float* __restrict__ w,
                                                            const float* __restrict__ sw,
                                                            bf16_t* __restrict__ out,
                                                            int R, int C) {
    __shared__ float tile[64][65];
    int z = blockIdx.z;
    const float* src = (z < NEXP) ? (w + (size_t)z * R * C) : sw;
    bf16_t* dst = out + (size_t)z * R * C;
    int c0 = blockIdx.x * 64, r0 = blockIdx.y * 64;
    int t = threadIdx.x;
    int lr = t >> 4, lc4 = (t & 15) * 4;
#pragma unroll
    for (int it = 0; it < 4; it++) {
        int r = lr + it * 16;
        float4 v = *(const float4*)&src[(size_t)(r0 + r) * C + c0 + lc4];
        tile[r][lc4 + 0] = v.x; tile[r][lc4 + 1] = v.y;
        tile[r][lc4 + 2] = v.z; tile[r][lc4 + 3] = v.w;
    }
    __syncthreads();
    int wc = t >> 2, wr8 = (t & 3) * 8;
#pragma unroll
    for (int it = 0; it < 2; it++) {
        int rr = wr8 + it * 32;
        bf16x8 o;
#pragma unroll
        for (int j = 0; j < 8; j++) o[j] = (bf16_t)tile[rr + j][wc];
        *(bf16x8*)&dst[(size_t)(c0 + wc) * R + r0 + rr] = o;
    }
}

// ---------------- GEMM1: 256m x 64n, 512 thr, XCD swizzle ----------------
// grid.x = 16m * 32n * 9z = 4608; xcd = id&7, m innermost within (z,n) group
__global__ __launch_bounds__(512) void gemm1_kernel(
    const bf16_t* __restrict__ xb, const bf16_t* __restrict__ B1base,
    const bf16_t* __restrict__ B3base, const int* __restrict__ cnt,
    const int* __restrict__ tok, bf16_t* __restrict__ act) {
    const int K = DMODEL, N = HIDDEN;
    int id = blockIdx.x;
    int v = (id & 7) * 576 + (id >> 3);
    int mb = v & 15; v >>= 4;
    int nb = v & 31; int z = v >> 5;
    const int m0 = mb * 256, n0 = nb * 64;
    int nrow;
    const int* tokz = nullptr;
    if (z < NEXP) {
        int c = cnt[z];
        nrow = c < CAPA ? c : CAPA;
        if (m0 >= nrow) return;
        tokz = tok + (size_t)z * CAPA;
    } else {
        nrow = T_TOK;
    }
    const bf16_t* B1 = B1base + (size_t)z * DMODEL * HIDDEN;
    const bf16_t* B3 = B3base + (size_t)z * DMODEL * HIDDEN;
    bf16_t* actz = act + (size_t)z * CAPA * HIDDEN;  // z==8 lands at 8*CAPA (shared region)

    __shared__ bf16_t sA[8192];   // [4 kc][256 m][8]
    __shared__ bf16_t sB1[2048];  // [4 kc][64 n][8]
    __shared__ bf16_t sB3[2048];
    const int tid = threadIdx.x, lane = tid & 63, wave = tid >> 6;
    const int quad = lane >> 4, l16 = lane & 15;
    const int wm = wave * 32;

    // A staging: 2 chunks/thread (16 KB)
    const bf16_t* ga[2]; int loA[2];
#pragma unroll
    for (int i = 0; i < 2; i++) {
        int q = i * 512 + tid;
        int c = q >> 8, mm = q & 255;
        int row;
        if (z < NEXP) { int s = m0 + mm; if (s >= nrow) s = nrow - 1; row = tokz[s]; }
        else row = m0 + mm;
        ga[i] = xb + (size_t)row * K + c * 8;
        loA[i] = (c * 256 + (mm & ~63)) * 8;  // wave-uniform base (lane adds 16B)
    }
    // B staging: waves 0-3 -> B1, waves 4-7 -> B3 (4 KB each)
    int bt = tid & 255;
    int bc = bt >> 6, bn = bt & 63;
    const bf16_t* gb = ((tid < 256) ? B1 : B3) + (size_t)(n0 + bn) * K + bc * 8;
    bf16_t* sBdst = ((tid < 256) ? sB1 : sB3) + (size_t)(bc * 64 + (bn & ~63)) * 8;

    f32x4 acc1[2][4], acc3[2][4];
#pragma unroll
    for (int i = 0; i < 2; i++)
#pragma unroll
        for (int j = 0; j < 4; j++) { acc1[i][j] = (f32x4)0.f; acc3[i][j] = (f32x4)0.f; }

    for (int k0 = 0; k0 < K; k0 += 32) {
        __syncthreads();
        gl_lds16(ga[0] + k0, &sA[loA[0]]);
        gl_lds16(ga[1] + k0, &sA[loA[1]]);
        gl_lds16(gb + k0, sBdst);
        __syncthreads();
        bf16x8 af[2];
#pragma unroll
        for (int mi = 0; mi < 2; mi++)
            af[mi] = *(const bf16x8*)&sA[(quad * 256 + wm + mi * 16 + l16) * 8];
#pragma unroll
        for (int nj = 0; nj < 4; nj++) {
            bf16x8 b1f = *(const bf16x8*)&sB1[(quad * 64 + nj * 16 + l16) * 8];
            bf16x8 b3f = *(const bf16x8*)&sB3[(quad * 64 + nj * 16 + l16) * 8];
#pragma unroll
            for (int mi = 0; mi < 2; mi++) {
                acc1[mi][nj] = __builtin_amdgcn_mfma_f32_16x16x32_bf16(af[mi], b1f, acc1[mi][nj], 0, 0, 0);
                acc3[mi][nj] = __builtin_amdgcn_mfma_f32_16x16x32_bf16(af[mi], b3f, acc3[mi][nj], 0, 0, 0);
            }
        }
    }
#pragma unroll
    for (int mi = 0; mi < 2; mi++)
#pragma unroll
        for (int r = 0; r < 4; r++) {
            int m = m0 + wm + mi * 16 + quad * 4 + r;
#pragma unroll
            for (int nj = 0; nj < 4; nj++) {
                int n = n0 + nj * 16 + l16;
                float h1 = acc1[mi][nj][r], h3 = acc3[mi][nj][r];
                float s = h1 / (1.f + __expf(-h1));
                actz[(size_t)m * N + n] = (bf16_t)(s * h3);
            }
        }
}

// ---------------- GEMM2 unified: yr[slot] = gate * (act @ w2), 256m x 128n ----------------
// grid.x = 16m * 8n * 9z = 1152
__global__ __launch_bounds__(512) void gemm2_kernel(const bf16_t* __restrict__ act,
                                                    const bf16_t* __restrict__ Bbase,
                                                    const int* __restrict__ cnt,
                                                    const float* __restrict__ gate,
                                                    bf16_t* __restrict__ yr) {
    const int K = HIDDEN, N = DMODEL;
    int id = blockIdx.x;
    int v = (id & 7) * 144 + (id >> 3);
    int mb = v & 15; v >>= 4;
    int nb = v & 7; int z = v >> 3;
    const int m0 = mb * 256, n0 = nb * 128;
    int nrow;
    if (z < NEXP) {
        int c = cnt[z];
        nrow = c < CAPA ? c : CAPA;
        if (m0 >= nrow) return;
    } else {
        nrow = T_TOK;
    }
    const bf16_t* A = act + (size_t)z * CAPA * K;   // z==8 -> shared region
    const bf16_t* B = Bbase + (size_t)z * DMODEL * HIDDEN;
    bf16_t* yrz = yr + (size_t)z * CAPA * N;

    __shared__ bf16_t sA[8192];  // [4][256][8]
    __shared__ bf16_t sB[4096];  // [4][128][8]
    const int tid = threadIdx.x, lane = tid & 63, wave = tid >> 6;
    const int quad = lane >> 4, l16 = lane & 15;
    const int wm = wave * 32;

    const bf16_t* ga[2]; int loA[2];
#pragma unroll
    for (int i = 0; i < 2; i++) {
        int q = i * 512 + tid;
        int c = q >> 8, mm = q & 255;
        ga[i] = A + (size_t)(m0 + mm) * K + c * 8;
        loA[i] = (c * 256 + (mm & ~63)) * 8;
    }
    int bc = tid >> 7, bn = tid & 127;
    const bf16_t* gb = B + (size_t)(n0 + bn) * K + bc * 8;
    bf16_t* sBdst = sB + (size_t)(bc * 128 + (bn & ~63)) * 8;

    f32x4 acc[2][8];
#pragma unroll
    for (int i = 0; i < 2; i++)
#pragma unroll
        for (int j = 0; j < 8; j++) acc[i][j] = (f32x4)0.f;

    for (int k0 = 0; k0 < K; k0 += 32) {
        __syncthreads();
        gl_lds16(ga[0] + k0, &sA[loA[0]]);
        gl_lds16(ga[1] + k0, &sA[loA[1]]);
        gl_lds16(gb + k0, sBdst);
        __syncthreads();
        bf16x8 af[2];
#pragma unroll
        for (int mi = 0; mi < 2; mi++)
            af[mi] = *(const bf16x8*)&sA[(quad * 256 + wm + mi * 16 + l16) * 8];
#pragma unroll
        for (int nj = 0; nj < 8; nj++) {
            bf16x8 bfr = *(const bf16x8*)&sB[(quad * 128 + nj * 16 + l16) * 8];
#pragma unroll
            for (int mi = 0; mi < 2; mi++)
                acc[mi][nj] = __builtin_amdgcn_mfma_f32_16x16x32_bf16(af[mi], bfr, acc[mi][nj], 0, 0, 0);
        }
    }
#pragma unroll
    for (int mi = 0; mi < 2; mi++)
#pragma unroll
        for (int r = 0; r < 4; r++) {
            int m = m0 + wm + mi * 16 + quad * 4 + r;
            if (z == NEXP) {
#pragma unroll
                for (int nj = 0; nj < 8; nj++) {
                    int n = n0 + nj * 16 + l16;
                    yrz[(size_t)m * N + n] = (bf16_t)acc[mi][nj][r];
                }
            } else if (m < nrow) {
                float g = gate[(size_t)z * CAPA + m];
#pragma unroll
                for (int nj = 0; nj < 8; nj++) {
                    int n = n0 + nj * 16 + l16;
                    yrz[(size_t)m * N + n] = (bf16_t)(g * acc[mi][nj][r]);
                }
            }
        }
}

// ---------------- combine: out[t] = yr_shared[t] + yr[p1] + yr[p2] ----------------
__global__ __launch_bounds__(256) void combine_kernel(const int2* __restrict__ pair,
                                                      const bf16_t* __restrict__ yr,
                                                      float* __restrict__ outp) {
    int t = blockIdx.x;
    int d = threadIdx.x * 4;
    int2 p = pair[t];
    const bf16_t* s = yr + ((size_t)NEXP * CAPA + t) * DMODEL + d;
    float o0 = (float)s[0], o1 = (float)s[1], o2 = (float)s[2], o3 = (float)s[3];
    if (p.x >= 0) {
        const bf16_t* r = yr + (size_t)p.x * DMODEL + d;
        o0 += (float)r[0]; o1 += (float)r[1]; o2 += (float)r[2]; o3 += (float)r[3];
    }
    if (p.y >= 0) {
        const bf16_t* r = yr + (size_t)p.y * DMODEL + d;
        o0 += (float)r[0]; o1 += (float)r[1]; o2 += (float)r[2]; o3 += (float)r[3];
    }
    float4 o = make_float4(o0, o1, o2, o3);
    *(float4*)(outp + (size_t)t * DMODEL + d) = o;
}

extern "C" void kernel_launch(void* const* d_in, const int* in_sizes, int n_in,
                              void* d_out, int out_size, void* d_ws, size_t ws_size,
                              hipStream_t stream) {
    (void)in_sizes; (void)n_in; (void)out_size; (void)ws_size;
    const float* x   = (const float*)d_in[0];
    const float* wr  = (const float*)d_in[1];
    const float* w1  = (const float*)d_in[2];
    const float* w3  = (const float*)d_in[3];
    const float* w2  = (const float*)d_in[4];
    const float* sw1 = (const float*)d_in[5];
    const float* sw3 = (const float*)d_in[6];
    const float* sw2 = (const float*)d_in[7];
    float* outp = (float*)d_out;

    const size_t TD = (size_t)T_TOK * DMODEL;
    const size_t DH = (size_t)DMODEL * HIDDEN;
    auto al = [](size_t b) { return (b + 255) & ~(size_t)255; };

    char* p = (char*)d_ws;
    size_t off = 0;
    auto alloc = [&](size_t b) { char* r = p + off; off += al(b); return r; };

    int* cnt    = (int*)alloc(NEXP * 4);
    int* tok    = (int*)alloc((size_t)NEXP * CAPA * 4);
    float* gate = (float*)alloc((size_t)NEXP * CAPA * 4);
    int2* pairp = (int2*)alloc((size_t)T_TOK * 8);
    bf16_t* xb  = (bf16_t*)alloc(TD * 2);                               // 8.4 MB

    const size_t wb_b  = 9 * DH * 2;                                    // 37.7 MB
    const size_t yr_b  = ((size_t)NEXP * CAPA + T_TOK) * DMODEL * 2;    // 29.4 MB
    const size_t act_b = ((size_t)NEXP * CAPA + T_TOK) * HIDDEN * 2;    // 58.7 MB

    // wb1 region is dead after gemm1 -> yr aliases it (yr_b < wb_b)
    char* wb1r  = alloc(wb_b);
    bf16_t* wb1 = (bf16_t*)wb1r;
    bf16_t* yrp = (bf16_t*)wb1r;
    bf16_t* wb3 = (bf16_t*)alloc(wb_b);
    bf16_t* wb2 = (bf16_t*)alloc(wb_b);
    bf16_t* act = (bf16_t*)alloc(act_b);
    (void)yr_b;
    // total ~181 MB (< the ~199.5 MB the batched path already used in R2/R3)

    hipMemsetAsync(cnt, 0, NEXP * 4, stream);
    cvt_x_kernel<<<dim3((unsigned)(TD / 8 / 256)), 256, 0, stream>>>(x, xb, (int)(TD / 8));
    router_kernel<<<dim3(T_TOK / 4), 256, 0, stream>>>(x, wr, cnt, tok, gate, pairp);
    transpose_cvt_kernel<<<dim3(HIDDEN / 64, DMODEL / 64, 9), 256, 0, stream>>>(w1, sw1, wb1, DMODEL, HIDDEN);
    transpose_cvt_kernel<<<dim3(HIDDEN / 64, DMODEL / 64, 9), 256, 0, stream>>>(w3, sw3, wb3, DMODEL, HIDDEN);
    transpose_cvt_kernel<<<dim3(DMODEL / 64, HIDDEN / 64, 9), 256, 0, stream>>>(w2, sw2, wb2, HIDDEN, DMODEL);
    gemm1_kernel<<<dim3(4608), 512, 0, stream>>>(xb, wb1, wb3, cnt, tok, act);
    gemm2_kernel<<<dim3(1152), 512, 0, stream>>>(act, wb2, cnt, gate, yrp);
    combine_kernel<<<dim3(T_TOK), 256, 0, stream>>>(pairp, yrp, outp);
}

// Round 5
// 770.181 us; speedup vs baseline: 1.4862x; 1.4862x over previous
//
#include <hip/hip_runtime.h>
#include <hip/hip_bf16.h>
#include <cstdint>
#include <cstddef>

#define T_TOK 4096
#define DMODEL 1024
#define HIDDEN 2048
#define NEXP 8      // routed experts; z==8 = shared
#define RTOT 8192   // total routed slots = T_TOK * topk (exact, compact)

typedef __bf16 bf16_t;
typedef bf16_t bf16x8 __attribute__((ext_vector_type(8)));
typedef float f32x16 __attribute__((ext_vector_type(16)));

__device__ __forceinline__ void gl_lds16(const void* g, void* l) {
    __builtin_amdgcn_global_load_lds(
        (const __attribute__((address_space(1))) unsigned int*)g,
        (__attribute__((address_space(3))) unsigned int*)l, 16, 0, 0);
}

// ---------------- x f32 -> bf16 (dense, for shared expert) ----------------
__global__ __launch_bounds__(256) void cvt_x_kernel(const float* __restrict__ x,
                                                    bf16_t* __restrict__ xb, int n8) {
    int i = blockIdx.x * 256 + threadIdx.x;
    if (i >= n8) return;
    const float4* v = (const float4*)(x + (size_t)i * 8);
    float4 a = v[0], b = v[1];
    bf16x8 o = {(bf16_t)a.x, (bf16_t)a.y, (bf16_t)a.z, (bf16_t)a.w,
                (bf16_t)b.x, (bf16_t)b.y, (bf16_t)b.z, (bf16_t)b.w};
    *(bf16x8*)(xb + (size_t)i * 8) = o;
}

// ---------------- router: top2 -> padded per-expert lists + per-token (e,p) pairs ----------------
__global__ __launch_bounds__(256) void router_kernel(const float* __restrict__ x,
                                                     const float* __restrict__ wr,
                                                     int* __restrict__ cnt,
                                                     int* __restrict__ tok,    // [8][4096]
                                                     float* __restrict__ gate, // [8][4096]
                                                     int4* __restrict__ pair) {
    int token = (blockIdx.x * 256 + threadIdx.x) >> 6;
    int lane = threadIdx.x & 63;
    if (token >= T_TOK) return;
    const float* xr = x + (size_t)token * DMODEL;
    float acc[8];
#pragma unroll
    for (int e = 0; e < 8; e++) acc[e] = 0.f;
    for (int d = lane; d < DMODEL; d += 64) {
        float xv = xr[d];
        const float* w = wr + d * 8;
#pragma unroll
        for (int e = 0; e < 8; e++) acc[e] += xv * w[e];
    }
#pragma unroll
    for (int e = 0; e < 8; e++) {
#pragma unroll
        for (int off = 32; off > 0; off >>= 1) acc[e] += __shfl_down(acc[e], off);
    }
    if (lane == 0) {
        int i1 = 0; float v1 = acc[0];
#pragma unroll
        for (int e = 1; e < 8; e++) if (acc[e] > v1) { v1 = acc[e]; i1 = e; }
        int i2 = -1; float v2 = -1e30f;
#pragma unroll
        for (int e = 0; e < 8; e++) if (e != i1 && acc[e] > v2) { v2 = acc[e]; i2 = e; }
        float g1 = 1.f / (1.f + __expf(v2 - v1));
        float g2 = 1.f - g1;
        int p1 = atomicAdd(&cnt[i1], 1);
        tok[i1 * T_TOK + p1] = token; gate[i1 * T_TOK + p1] = g1;
        int p2 = atomicAdd(&cnt[i2], 1);
        tok[i2 * T_TOK + p2] = token; gate[i2 * T_TOK + p2] = g2;
        pair[token] = make_int4(i1, p1, i2, p2);
    }
}

// ---------------- prefix: offs[e] = cumsum(cnt) ----------------
__global__ void prefix_kernel(const int* __restrict__ cnt, int* __restrict__ offs) {
    if (threadIdx.x == 0) {
        int a = 0;
        for (int e = 0; e < NEXP; e++) { offs[e] = a; a += cnt[e]; }
        offs[NEXP] = a;
    }
}

// ---------------- gather: xg[offs[z]+s] = bf16(x[tok[z][s]]) (compact, dense rows) ----------------
__global__ __launch_bounds__(256) void gather_kernel(const float* __restrict__ x,
                                                     const int* __restrict__ cnt,
                                                     const int* __restrict__ offs,
                                                     const int* __restrict__ tok,
                                                     bf16_t* __restrict__ xg) {
    int sg = blockIdx.x * 2 + (threadIdx.x >> 7);
    int z = sg >> 12, s = sg & 4095;
    if (s >= cnt[z]) return;
    int t = tok[z * T_TOK + s];
    int c = threadIdx.x & 127;
    const float4* v = (const float4*)(x + (size_t)t * DMODEL + c * 8);
    float4 a = v[0], b = v[1];
    bf16x8 o = {(bf16_t)a.x, (bf16_t)a.y, (bf16_t)a.z, (bf16_t)a.w,
                (bf16_t)b.x, (bf16_t)b.y, (bf16_t)b.z, (bf16_t)b.w};
    *(bf16x8*)(xg + ((size_t)offs[z] + s) * DMODEL + c * 8) = o;
}

// ---------------- transpose+cvt: f32 [R][C] -> bf16 [C][R]; 128B-coalesced writes ----------------
__global__ __launch_bounds__(256) void transpose_cvt_kernel(const float* __restrict__ w,
                                                            const float* __restrict__ sw,
                                                            bf16_t* __restrict__ out,
                                                            int R, int C) {
    __shared__ float tile[64][65];
    int z = blockIdx.z;
    const float* src = (z < NEXP) ? (w + (size_t)z * R * C) : sw;
    bf16_t* dst = out + (size_t)z * R * C;
    int c0 = blockIdx.x * 64, r0 = blockIdx.y * 64;
    int t = threadIdx.x;
    int lr = t >> 4, lc4 = (t & 15) * 4;
#pragma unroll
    for (int it = 0; it < 4; it++) {
        int r = lr + it * 16;
        float4 v = *(const float4*)&src[(size_t)(r0 + r) * C + c0 + lc4];
        tile[r][lc4 + 0] = v.x; tile[r][lc4 + 1] = v.y;
        tile[r][lc4 + 2] = v.z; tile[r][lc4 + 3] = v.w;
    }
    __syncthreads();
    int wave = t >> 6, lane = t & 63;
#pragma unroll
    for (int it = 0; it < 2; it++) {
        int col = wave * 8 + (lane >> 3) + it * 32;
        int rb = (lane & 7) * 8;
        bf16x8 o;
#pragma unroll
        for (int j = 0; j < 8; j++) o[j] = (bf16_t)tile[rb + j][col];
        *(bf16x8*)&dst[(size_t)(c0 + col) * R + r0 + rb] = o;
    }
}

// ---------------- GEMM1: act = silu(xg@w1)*(xg@w3); 128m x 64n, 32x32x16 MFMA ----------------
// waves: wm=(wave>>1)*64 (2 m-tiles of 32), wn=(wave&1)*32; dual acc = 64 AGPR
__global__ __launch_bounds__(256) void gemm1_kernel(
    const bf16_t* __restrict__ xg, const bf16_t* __restrict__ xb,
    const bf16_t* __restrict__ B1base, const bf16_t* __restrict__ B3base,
    const int* __restrict__ cnt, const int* __restrict__ offs,
    bf16_t* __restrict__ act) {
    const int K = DMODEL, N = HIDDEN;
    const int z = blockIdx.z;
    const int n0 = blockIdx.x * 64, m0 = blockIdx.y * 128;
    int nrow; const bf16_t* Abase; bf16_t* actz;
    if (z < NEXP) {
        nrow = cnt[z];
        if (m0 >= nrow) return;
        int o = offs[z];
        Abase = xg + (size_t)o * K;
        actz = act + (size_t)o * N;
    } else {
        nrow = T_TOK; Abase = xb; actz = act + (size_t)RTOT * N;
    }
    const bf16_t* B1 = B1base + (size_t)z * DMODEL * HIDDEN;
    const bf16_t* B3 = B3base + (size_t)z * DMODEL * HIDDEN;

    __shared__ bf16_t sA[4096];   // [4 kc][128 m][8]
    __shared__ bf16_t sB1[2048];  // [4 kc][64 n][8]
    __shared__ bf16_t sB3[2048];
    const int tid = threadIdx.x, lane = tid & 63, wave = tid >> 6;
    const int hi = lane >> 5, l31 = lane & 31;
    const int wm = (wave >> 1) * 64, wn = (wave & 1) * 32;

    const bf16_t* ga[2]; int loA[2];
#pragma unroll
    for (int i = 0; i < 2; i++) {
        int q = i * 256 + tid;
        int c = q >> 7, mm = q & 127;
        ga[i] = Abase + (size_t)(m0 + mm) * K + c * 8;
        loA[i] = ((i * 2 + (wave >> 1)) * 128 + (wave & 1) * 64) * 8;
    }
    const bf16_t* gb1 = B1 + (size_t)(n0 + lane) * K + wave * 8;
    const bf16_t* gb3 = B3 + (size_t)(n0 + lane) * K + wave * 8;
    const int loB = wave * 64 * 8;

    f32x16 acc1[2], acc3[2];
#pragma unroll
    for (int i = 0; i < 2; i++) { acc1[i] = (f32x16)0.f; acc3[i] = (f32x16)0.f; }

    for (int k0 = 0; k0 < K; k0 += 32) {
        __syncthreads();
        gl_lds16(ga[0] + k0, &sA[loA[0]]);
        gl_lds16(ga[1] + k0, &sA[loA[1]]);
        gl_lds16(gb1 + k0, &sB1[loB]);
        gl_lds16(gb3 + k0, &sB3[loB]);
        __syncthreads();
#pragma unroll
        for (int s = 0; s < 2; s++) {
            int kc = s * 2 + hi;
            bf16x8 a0 = *(const bf16x8*)&sA[(kc * 128 + wm + l31) * 8];
            bf16x8 a1 = *(const bf16x8*)&sA[(kc * 128 + wm + 32 + l31) * 8];
            bf16x8 b1f = *(const bf16x8*)&sB1[(kc * 64 + wn + l31) * 8];
            bf16x8 b3f = *(const bf16x8*)&sB3[(kc * 64 + wn + l31) * 8];
            acc1[0] = __builtin_amdgcn_mfma_f32_32x32x16_bf16(a0, b1f, acc1[0], 0, 0, 0);
            acc1[1] = __builtin_amdgcn_mfma_f32_32x32x16_bf16(a1, b1f, acc1[1], 0, 0, 0);
            acc3[0] = __builtin_amdgcn_mfma_f32_32x32x16_bf16(a0, b3f, acc3[0], 0, 0, 0);
            acc3[1] = __builtin_amdgcn_mfma_f32_32x32x16_bf16(a1, b3f, acc3[1], 0, 0, 0);
        }
    }
    // C/D: col=lane&31, row=(reg&3)+8*(reg>>2)+4*(lane>>5)
#pragma unroll
    for (int mt = 0; mt < 2; mt++)
#pragma unroll
        for (int reg = 0; reg < 16; reg++) {
            int m = m0 + wm + mt * 32 + (reg & 3) + 8 * (reg >> 2) + 4 * hi;
            if (m < nrow) {
                int n = n0 + wn + l31;
                float h1 = acc1[mt][reg], h3 = acc3[mt][reg];
                float si = h1 / (1.f + __expf(-h1));
                actz[(size_t)m * N + n] = (bf16_t)(si * h3);
            }
        }
}

// ---------------- GEMM2: 128m x 128n, 32x32x16; z<8 -> yr (gated bf16); z==8 -> d_out f32 ----------------
__global__ __launch_bounds__(256) void gemm2_kernel(const bf16_t* __restrict__ act,
                                                    const bf16_t* __restrict__ Bbase,
                                                    const int* __restrict__ cnt,
                                                    const int* __restrict__ offs,
                                                    const float* __restrict__ gate,
                                                    bf16_t* __restrict__ yr,
                                                    float* __restrict__ outp) {
    const int K = HIDDEN, N = DMODEL;
    const int z = blockIdx.z;
    const int n0 = blockIdx.x * 128, m0 = blockIdx.y * 128;
    int nrow, o;
    if (z < NEXP) {
        nrow = cnt[z];
        if (m0 >= nrow) return;
        o = offs[z];
    } else {
        nrow = T_TOK; o = RTOT;
    }
    const bf16_t* A = act + (size_t)o * K;
    const bf16_t* B = Bbase + (size_t)z * DMODEL * HIDDEN;

    __shared__ bf16_t sA[4096], sB[4096];  // [4][128][8]
    const int tid = threadIdx.x, lane = tid & 63, wave = tid >> 6;
    const int hi = lane >> 5, l31 = lane & 31;
    const int wm = (wave >> 1) * 64, wn = (wave & 1) * 64;

    const bf16_t* ga[2]; const bf16_t* gb[2]; int lo[2];
#pragma unroll
    for (int i = 0; i < 2; i++) {
        int q = i * 256 + tid;
        int c = q >> 7, mm = q & 127;
        ga[i] = A + (size_t)(m0 + mm) * K + c * 8;
        gb[i] = B + (size_t)(n0 + mm) * K + c * 8;
        lo[i] = ((i * 2 + (wave >> 1)) * 128 + (wave & 1) * 64) * 8;
    }
    f32x16 acc[2][2];
#pragma unroll
    for (int i = 0; i < 2; i++)
#pragma unroll
        for (int j = 0; j < 2; j++) acc[i][j] = (f32x16)0.f;

    for (int k0 = 0; k0 < K; k0 += 32) {
        __syncthreads();
        gl_lds16(ga[0] + k0, &sA[lo[0]]);
        gl_lds16(ga[1] + k0, &sA[lo[1]]);
        gl_lds16(gb[0] + k0, &sB[lo[0]]);
        gl_lds16(gb[1] + k0, &sB[lo[1]]);
        __syncthreads();
#pragma unroll
        for (int s = 0; s < 2; s++) {
            int kc = s * 2 + hi;
            bf16x8 a0 = *(const bf16x8*)&sA[(kc * 128 + wm + l31) * 8];
            bf16x8 a1 = *(const bf16x8*)&sA[(kc * 128 + wm + 32 + l31) * 8];
            bf16x8 b0 = *(const bf16x8*)&sB[(kc * 128 + wn + l31) * 8];
            bf16x8 b1 = *(const bf16x8*)&sB[(kc * 128 + wn + 32 + l31) * 8];
            acc[0][0] = __builtin_amdgcn_mfma_f32_32x32x16_bf16(a0, b0, acc[0][0], 0, 0, 0);
            acc[0][1] = __builtin_amdgcn_mfma_f32_32x32x16_bf16(a0, b1, acc[0][1], 0, 0, 0);
            acc[1][0] = __builtin_amdgcn_mfma_f32_32x32x16_bf16(a1, b0, acc[1][0], 0, 0, 0);
            acc[1][1] = __builtin_amdgcn_mfma_f32_32x32x16_bf16(a1, b1, acc[1][1], 0, 0, 0);
        }
    }
#pragma unroll
    for (int mt = 0; mt < 2; mt++)
#pragma unroll
        for (int reg = 0; reg < 16; reg++) {
            int m = m0 + wm + mt * 32 + (reg & 3) + 8 * (reg >> 2) + 4 * hi;
            if (z == NEXP) {
#pragma unroll
                for (int nt = 0; nt < 2; nt++) {
                    int n = n0 + wn + nt * 32 + l31;
                    outp[(size_t)m * N + n] = acc[mt][nt][reg];
                }
            } else if (m < nrow) {
                float g = gate[z * T_TOK + m];
#pragma unroll
                for (int nt = 0; nt < 2; nt++) {
                    int n = n0 + wn + nt * 32 + l31;
                    yr[((size_t)o + m) * N + n] = (bf16_t)(g * acc[mt][nt][reg]);
                }
            }
        }
}

// ---------------- combine: out[t] += yr[offs[e1]+p1] + yr[offs[e2]+p2] ----------------
__global__ __launch_bounds__(256) void combine_kernel(const int4* __restrict__ pair,
                                                      const int* __restrict__ offs,
                                                      const bf16_t* __restrict__ yr,
                                                      float* __restrict__ outp) {
    int t = blockIdx.x;
    int d = threadIdx.x * 4;
    int4 p = pair[t];
    size_t i1 = (size_t)(offs[p.x] + p.y) * DMODEL + d;
    size_t i2 = (size_t)(offs[p.z] + p.w) * DMODEL + d;
    float* op = outp + (size_t)t * DMODEL + d;
    float4 o = *(float4*)op;
    o.x += (float)yr[i1 + 0] + (float)yr[i2 + 0];
    o.y += (float)yr[i1 + 1] + (float)yr[i2 + 1];
    o.z += (float)yr[i1 + 2] + (float)yr[i2 + 2];
    o.w += (float)yr[i1 + 3] + (float)yr[i2 + 3];
    *(float4*)op = o;
}

extern "C" void kernel_launch(void* const* d_in, const int* in_sizes, int n_in,
                              void* d_out, int out_size, void* d_ws, size_t ws_size,
                              hipStream_t stream) {
    (void)in_sizes; (void)n_in; (void)out_size; (void)ws_size;
    const float* x   = (const float*)d_in[0];
    const float* wr  = (const float*)d_in[1];
    const float* w1  = (const float*)d_in[2];
    const float* w3  = (const float*)d_in[3];
    const float* w2  = (const float*)d_in[4];
    const float* sw1 = (const float*)d_in[5];
    const float* sw3 = (const float*)d_in[6];
    const float* sw2 = (const float*)d_in[7];
    float* outp = (float*)d_out;

    const size_t TD = (size_t)T_TOK * DMODEL;
    const size_t DH = (size_t)DMODEL * HIDDEN;
    auto al = [](size_t b) { return (b + 255) & ~(size_t)255; };

    char* p = (char*)d_ws;
    size_t off = 0;
    auto alloc = [&](size_t b) { char* r = p + off; off += al(b); return r; };

    int* cnt    = (int*)alloc(NEXP * 4);
    int* offs   = (int*)alloc((NEXP + 1) * 4);
    int* tok    = (int*)alloc((size_t)NEXP * T_TOK * 4);
    float* gate = (float*)alloc((size_t)NEXP * T_TOK * 4);
    int4* pairp = (int4*)alloc((size_t)T_TOK * 16);
    bf16_t* xb  = (bf16_t*)alloc(TD * 2);                      // 8.39 MB
    bf16_t* xg  = (bf16_t*)alloc((size_t)RTOT * DMODEL * 2);   // 16.78 MB

    const size_t wb_b = 9 * DH * 2;                            // 37.75 MB each
    const size_t yr_b = (size_t)RTOT * DMODEL * 2;             // 16.78 MB (aliases wb1)
    (void)yr_b;
    char* wb1r  = alloc(wb_b);
    bf16_t* wb1 = (bf16_t*)wb1r;   // dead after gemm1
    bf16_t* yrp = (bf16_t*)wb1r;   // live gemm2..combine
    bf16_t* wb3 = (bf16_t*)alloc(wb_b);
    bf16_t* wb2 = (bf16_t*)alloc(wb_b);
    bf16_t* act = (bf16_t*)alloc(((size_t)RTOT + T_TOK) * HIDDEN * 2);  // 50.33 MB
    // total ~189 MB < proven-available 199.3 MB

    hipMemsetAsync(cnt, 0, NEXP * 4, stream);
    cvt_x_kernel<<<dim3((unsigned)(TD / 8 / 256)), 256, 0, stream>>>(x, xb, (int)(TD / 8));
    router_kernel<<<dim3(T_TOK / 4), 256, 0, stream>>>(x, wr, cnt, tok, gate, pairp);
    prefix_kernel<<<dim3(1), 64, 0, stream>>>(cnt, offs);
    gather_kernel<<<dim3(NEXP * T_TOK / 2), 256, 0, stream>>>(x, cnt, offs, tok, xg);
    transpose_cvt_kernel<<<dim3(HIDDEN / 64, DMODEL / 64, 9), 256, 0, stream>>>(w1, sw1, wb1, DMODEL, HIDDEN);
    transpose_cvt_kernel<<<dim3(HIDDEN / 64, DMODEL / 64, 9), 256, 0, stream>>>(w3, sw3, wb3, DMODEL, HIDDEN);
    transpose_cvt_kernel<<<dim3(DMODEL / 64, HIDDEN / 64, 9), 256, 0, stream>>>(w2, sw2, wb2, HIDDEN, DMODEL);
    gemm1_kernel<<<dim3(HIDDEN / 64, T_TOK / 128, 9), 256, 0, stream>>>(xg, xb, wb1, wb3, cnt, offs, act);
    gemm2_kernel<<<dim3(DMODEL / 128, T_TOK / 128, 9), 256, 0, stream>>>(act, wb2, cnt, offs, gate, yrp, outp);
    combine_kernel<<<dim3(T_TOK), 256, 0, stream>>>(pairp, offs, yrp, outp);
}